// Round 7
// baseline (213.425 us; speedup 1.0000x reference)
//
#include <hip/hip_runtime.h>
#include <hip/hip_cooperative_groups.h>
#include <math.h>

// LayerSumSimple: K-level chained cummax-of-sums == max-plus affine scan with
// 8-element state s:  s[k] <- max(s[k], s[k-1] + g_k(t)),  g_k = x*w[k]+b[k].
// Round-13: C=128 5-pass skeleton (C=256 regressed: +6us pass1 stores, +13us
// pass2 traffic). Two independent changes vs round-3:
//  (1) pass1: BAND-2 FUSED pair-steps. Two elementary steps compose to
//      s''[k] = max(s[k], s[k-1]+d1[k], s[k-2]+d2[k]) with d1[k]=max(gk,hk),
//      d2[k]=g_{k-1}+h_k  -> every update is a 3-input max = v_max3_f32.
//      58 ops/step vs 72 (-19% VALU issue; identical results).
//  (2) pass2a/2b/2c glued into ONE cooperative kernel (grid.sync between
//      phases, bodies verbatim) - removes 2 launches + 2 gaps.
// All workspace arrays use PLANE layout: plane i of region r at
// base[r*NPLANES*DD + i*DD + d] -> lane d accesses are fully coalesced.
namespace cg = cooperative_groups;
namespace {
constexpr int BB   = 8;
constexpr int TT   = 8192;
constexpr int DD   = 256;
constexpr int KK   = 8;
constexpr int TOUT = TT - KK + 1;       // 8185
constexpr int NSUM = 36;                // 8 c-vec + 28 strict-lower A
constexpr int C    = 128;               // chunks per sequence
constexpr int L    = TT / C;            // 64
constexpr int G    = 8;                 // chunks per group
constexpr int NG   = C / G;             // 16
constexpr int MSTR = NSUM * DD;         // float stride between map regions

// strict-lower-triangle linear index: k in [1,8), j < k  ->  [0,28)
__host__ __device__ __forceinline__ constexpr int alin(int k, int j) {
    return k * (k - 1) / 2 + j;
}
// plane index of A[k][j] in the 36-plane map layout (planes 0..7 = c-vec)
__host__ __device__ __forceinline__ constexpr int tri(int k, int j) {
    return 8 + alin(k, j);
}

__device__ __forceinline__ float max3(float a, float b, float c) {
    return fmaxf(fmaxf(a, b), c);       // clang fuses to v_max3_f32
}

// TWO fused time-steps of the summary recurrence (band-2 pair map applied to
// the accumulated triangular map). Descending k: rows k-1,k-2 read OLD values.
__device__ __forceinline__ void pair_sum(float xa, float xb,
                                         const float (&wk)[KK],
                                         const float (&bk)[KK],
                                         float (&a)[28], float (&cv)[KK])
{
    float gA[KK], gB[KK], d1[KK], d2[KK];   // d2 valid for k>=1
    #pragma unroll
    for (int k = 0; k < KK; ++k) gA[k] = fmaf(xa, wk[k], bk[k]);
    #pragma unroll
    for (int k = 0; k < KK; ++k) gB[k] = fmaf(xb, wk[k], bk[k]);
    #pragma unroll
    for (int k = 0; k < KK; ++k) d1[k] = fmaxf(gA[k], gB[k]);
    #pragma unroll
    for (int k = 1; k < KK; ++k) d2[k] = gA[k - 1] + gB[k];

    #pragma unroll
    for (int k = KK - 1; k >= 2; --k) {
        #pragma unroll
        for (int j = 0; j <= k - 3; ++j)
            a[alin(k, j)] = max3(a[alin(k, j)], d1[k] + a[alin(k - 1, j)],
                                 d2[k] + a[alin(k - 2, j)]);
        // j = k-2: diag a[k-2][k-2] == 0
        a[alin(k, k - 2)] = max3(a[alin(k, k - 2)],
                                 d1[k] + a[alin(k - 1, k - 2)], d2[k]);
        // j = k-1: diag a[k-1][k-1] == 0; a[k-2][k-1] = -inf
        a[alin(k, k - 1)] = fmaxf(a[alin(k, k - 1)], d1[k]);
        cv[k] = max3(cv[k], d1[k] + cv[k - 1], d2[k] + cv[k - 2]);
    }
    a[alin(1, 0)] = fmaxf(a[alin(1, 0)], d1[1]);
    cv[1] = max3(cv[1], d1[1] + cv[0], d2[1]);
    cv[0] = fmaxf(cv[0], d1[0]);
}

// ---- pass 1: one block per (b, chunk); thread d = channel ----
__global__ __launch_bounds__(256) void pass1_summaries(
    const float* __restrict__ X, const float* __restrict__ W,
    const float* __restrict__ Bv, float* __restrict__ sum)
{
    constexpr int U  = 8;
    constexpr int NB = L / U;           // 8
    const int b = blockIdx.x / C;
    const int c = blockIdx.x % C;
    const int d = threadIdx.x;

    float wk[KK], bk[KK];
    #pragma unroll
    for (int k = 0; k < KK; ++k) { wk[k] = W[k * DD + d]; bk[k] = Bv[k * DD + d]; }

    float cv[KK];
    float a[28];
    #pragma unroll
    for (int k = 0; k < KK; ++k) cv[k] = -INFINITY;
    #pragma unroll
    for (int i = 0; i < 28; ++i) a[i] = -INFINITY;

    const float* xp = X + ((size_t)(b * TT + c * L)) * DD + d;
    float x0[U], x1[U];
    #pragma unroll
    for (int u = 0; u < U; ++u) x0[u] = xp[u * DD];

    // dynamic loop: 16-step body; prefetch distance = 8 steps
    #pragma unroll 1
    for (int ib = 0; ib + 2 < NB; ib += 2) {
        #pragma unroll
        for (int u = 0; u < U; ++u) x1[u] = xp[(U + u) * DD];
        #pragma unroll
        for (int u = 0; u < U / 2; ++u) pair_sum(x0[2 * u], x0[2 * u + 1], wk, bk, a, cv);
        #pragma unroll
        for (int u = 0; u < U; ++u) x0[u] = xp[(2 * U + u) * DD];
        #pragma unroll
        for (int u = 0; u < U / 2; ++u) pair_sum(x1[2 * u], x1[2 * u + 1], wk, bk, a, cv);
        xp += 2 * U * DD;
    }
    // tail: batches NB-2 (in x0) and NB-1
    #pragma unroll
    for (int u = 0; u < U; ++u) x1[u] = xp[(U + u) * DD];
    #pragma unroll
    for (int u = 0; u < U / 2; ++u) pair_sum(x0[2 * u], x0[2 * u + 1], wk, bk, a, cv);
    #pragma unroll
    for (int u = 0; u < U / 2; ++u) pair_sum(x1[2 * u], x1[2 * u + 1], wk, bk, a, cv);

    // plane-layout store: 36 coalesced 1KB stores
    float* sp = sum + (size_t)blockIdx.x * MSTR + d;   // region = b*C + c
    #pragma unroll
    for (int k = 0; k < KK; ++k) sp[k * DD] = cv[k];
    #pragma unroll
    for (int i = 0; i < 28; ++i) sp[(8 + i) * DD] = a[i];
}

// plane-layout map load: 36 coalesced scalar loads into registers
__device__ __forceinline__ void ld_map(const float* __restrict__ p,
                                       float (&m)[NSUM])
{
    #pragma unroll
    for (int i = 0; i < NSUM; ++i) m[i] = p[i * DD];
}

// s <- apply(map m, s)
__device__ __forceinline__ void apply_map(const float (&m)[NSUM], float (&s)[KK])
{
    float ns[KK];
    #pragma unroll
    for (int k = 0; k < KK; ++k) ns[k] = fmaxf(m[k], s[k]);   // c[k], diag
    #pragma unroll
    for (int k = 1; k < KK; ++k) {
        #pragma unroll
        for (int j = 0; j < k; ++j) ns[k] = fmaxf(ns[k], m[tri(k, j)] + s[j]);
    }
    #pragma unroll
    for (int k = 0; k < KK; ++k) s[k] = ns[k];
}

// (R,cv) <- compose(map m, (R,cv))   [m applied AFTER accumulated (R,cv)]
__device__ __forceinline__ void compose_map(const float (&m)[NSUM],
                                            float (&R)[KK][KK], float (&cv)[KK])
{
    float nc[KK];
    #pragma unroll
    for (int i = 0; i < KK; ++i) {
        float v = fmaxf(m[i], cv[i]);
        #pragma unroll
        for (int j = 0; j < i; ++j) v = fmaxf(v, m[tri(i, j)] + cv[j]);
        nc[i] = v;
    }
    float nR[KK][KK];
    #pragma unroll
    for (int i = 1; i < KK; ++i) {
        #pragma unroll
        for (int j = 0; j < i; ++j) {
            float v = fmaxf(R[i][j], m[tri(i, j)]);
            #pragma unroll
            for (int mm = j + 1; mm < i; ++mm)
                v = fmaxf(v, m[tri(i, mm)] + R[mm][j]);
            nR[i][j] = v;
        }
    }
    #pragma unroll
    for (int i = 0; i < KK; ++i) {
        cv[i] = nc[i];
        #pragma unroll
        for (int j = 0; j < i; ++j) R[i][j] = nR[i][j];
    }
}

// ---- pass 2 (cooperative, 128 blocks): 2a compose -> sync -> 2b serial group
//      scan (blocks 0..7) -> sync -> 2c replay chunk inflows. Bodies verbatim
//      from the verified 3-kernel version. ----
__global__ __launch_bounds__(256) void pass2_fused(
    const float* __restrict__ sum, float* __restrict__ gsum,
    float* __restrict__ ginfl, float* __restrict__ infl)
{
    cg::grid_group grid = cg::this_grid();
    const int d = threadIdx.x;

    // ---- phase 2a: one block per (b, group); compose G chunk maps ----
    {
        const int b = blockIdx.x / NG;
        const int g = blockIdx.x % NG;

        float R[KK][KK], cv[KK];
        #pragma unroll
        for (int i = 0; i < KK; ++i) {
            cv[i] = -INFINITY;
            #pragma unroll
            for (int j = 0; j < KK; ++j) R[i][j] = -INFINITY;
        }

        const float* mp = sum + ((size_t)(b * C + g * G)) * MSTR + d;
        float m0[NSUM], m1[NSUM];
        ld_map(mp, m0);
        #pragma unroll 1
        for (int ci = 0; ci + 2 < G; ci += 2) {
            ld_map(mp + MSTR, m1);
            compose_map(m0, R, cv);
            ld_map(mp + 2 * MSTR, m0);
            compose_map(m1, R, cv);
            mp += 2 * MSTR;
        }
        ld_map(mp + MSTR, m1);
        compose_map(m0, R, cv);
        compose_map(m1, R, cv);

        float* gp = gsum + (size_t)blockIdx.x * MSTR + d;  // region = b*NG + g
        #pragma unroll
        for (int i = 0; i < KK; ++i) gp[i * DD] = cv[i];
        #pragma unroll
        for (int i = 1; i < KK; ++i) {
            #pragma unroll
            for (int j = 0; j < i; ++j) gp[tri(i, j) * DD] = R[i][j];
        }
    }

    grid.sync();

    // ---- phase 2b: blocks 0..BB-1; serial apply over NG group maps ----
    if (blockIdx.x < BB) {
        const int b = blockIdx.x;
        float s[KK];
        #pragma unroll
        for (int k = 0; k < KK; ++k) s[k] = -INFINITY;

        const float* mp = gsum + (size_t)b * NG * MSTR + d;
        float* ip = ginfl + (size_t)b * NG * KK * DD + d;
        float m0[NSUM], m1[NSUM];
        ld_map(mp, m0);
        #pragma unroll 1
        for (int g = 0; g + 2 < NG; g += 2) {
            ld_map(mp + MSTR, m1);
            #pragma unroll
            for (int k = 0; k < KK; ++k) ip[k * DD] = s[k];      // inflow BEFORE g
            apply_map(m0, s);
            ld_map(mp + 2 * MSTR, m0);
            #pragma unroll
            for (int k = 0; k < KK; ++k) ip[KK * DD + k * DD] = s[k];
            apply_map(m1, s);
            mp += 2 * MSTR;
            ip += 2 * KK * DD;
        }
        ld_map(mp + MSTR, m1);
        #pragma unroll
        for (int k = 0; k < KK; ++k) ip[k * DD] = s[k];
        apply_map(m0, s);
        #pragma unroll
        for (int k = 0; k < KK; ++k) ip[KK * DD + k * DD] = s[k];
        apply_map(m1, s);
    }

    grid.sync();

    // ---- phase 2c: one block per (b, group); replay chunk maps -> inflows ----
    {
        const int b = blockIdx.x / NG;
        const int g = blockIdx.x % NG;

        float s[KK];
        {
            const float* gp = ginfl + (size_t)blockIdx.x * KK * DD + d;
            #pragma unroll
            for (int k = 0; k < KK; ++k) s[k] = gp[k * DD];
        }

        const float* mp = sum + ((size_t)(b * C + g * G)) * MSTR + d;
        float* ip = infl + ((size_t)(b * C + g * G)) * KK * DD + d;
        float m0[NSUM], m1[NSUM];
        ld_map(mp, m0);
        #pragma unroll 1
        for (int ci = 0; ci + 2 < G; ci += 2) {
            ld_map(mp + MSTR, m1);
            #pragma unroll
            for (int k = 0; k < KK; ++k) ip[k * DD] = s[k];      // inflow BEFORE c
            apply_map(m0, s);
            ld_map(mp + 2 * MSTR, m0);
            #pragma unroll
            for (int k = 0; k < KK; ++k) ip[KK * DD + k * DD] = s[k];
            apply_map(m1, s);
            mp += 2 * MSTR;
            ip += 2 * KK * DD;
        }
        ld_map(mp + MSTR, m1);
        #pragma unroll
        for (int k = 0; k < KK; ++k) ip[k * DD] = s[k];
        apply_map(m0, s);
        #pragma unroll
        for (int k = 0; k < KK; ++k) ip[KK * DD + k * DD] = s[k];
        apply_map(m1, s);
    }
}

// ---- pass 3: one block per (b, chunk); scan from inflow, emit outputs ----
__device__ __forceinline__ void step_scan(float x, const float (&wk)[KK],
                                          const float (&bk)[KK], float (&s)[KK])
{
    float g[KK];
    #pragma unroll
    for (int k = 0; k < KK; ++k) g[k] = fmaf(x, wk[k], bk[k]);
    #pragma unroll
    for (int k = KK - 1; k >= 1; --k) s[k] = fmaxf(s[k], s[k - 1] + g[k]);
    s[0] = fmaxf(s[0], g[0]);
}

__global__ __launch_bounds__(256) void pass3_scan(
    const float* __restrict__ X, const float* __restrict__ W,
    const float* __restrict__ Bv, const float* __restrict__ infl,
    float* __restrict__ out)
{
    constexpr int U  = 16;              // deep prefetch: 16 rows in flight
    constexpr int NB = L / U;           // 4
    const int b = blockIdx.x / C;
    const int c = blockIdx.x % C;
    const int d = threadIdx.x;

    float wk[KK], bk[KK];
    #pragma unroll
    for (int k = 0; k < KK; ++k) { wk[k] = W[k * DD + d]; bk[k] = Bv[k * DD + d]; }

    float s[KK];
    {
        const float* ip = infl + (size_t)blockIdx.x * KK * DD + d;   // region = b*C+c
        #pragma unroll
        for (int k = 0; k < KK; ++k) s[k] = ip[k * DD];
    }

    const int t0 = c * L;
    const float* xp = X + ((size_t)(b * TT + t0)) * DD + d;
    // base indexed by cumulative in-chunk step t only (op never advances)
    float* op = out + (size_t)b * TOUT * DD + (ptrdiff_t)(t0 - (KK - 1)) * DD + d;

    float x0[U], x1[U];
    #pragma unroll
    for (int u = 0; u < U; ++u) x0[u] = xp[u * DD];

    int t = 0;                                   // step within chunk
    #pragma unroll 1
    for (int ib = 0; ib + 2 < NB; ib += 2) {
        #pragma unroll
        for (int u = 0; u < U; ++u) x1[u] = xp[(U + u) * DD];
        #pragma unroll
        for (int u = 0; u < U; ++u) {
            step_scan(x0[u], wk, bk, s);
            if (t0 + t >= KK - 1) __builtin_nontemporal_store(s[KK - 1], &op[t * DD]);
            ++t;
        }
        #pragma unroll
        for (int u = 0; u < U; ++u) x0[u] = xp[(2 * U + u) * DD];
        #pragma unroll
        for (int u = 0; u < U; ++u) {
            step_scan(x1[u], wk, bk, s);
            if (t0 + t >= KK - 1) __builtin_nontemporal_store(s[KK - 1], &op[t * DD]);
            ++t;
        }
        xp += 2 * U * DD;
    }
    #pragma unroll
    for (int u = 0; u < U; ++u) x1[u] = xp[(U + u) * DD];
    #pragma unroll
    for (int u = 0; u < U; ++u) {
        step_scan(x0[u], wk, bk, s);
        if (t0 + t >= KK - 1) __builtin_nontemporal_store(s[KK - 1], &op[t * DD]);
        ++t;
    }
    #pragma unroll
    for (int u = 0; u < U; ++u) {
        step_scan(x1[u], wk, bk, s);
        if (t0 + t >= KK - 1) __builtin_nontemporal_store(s[KK - 1], &op[t * DD]);
        ++t;
    }
}
} // namespace

extern "C" void kernel_launch(void* const* d_in, const int* in_sizes, int n_in,
                              void* d_out, int out_size, void* d_ws, size_t ws_size,
                              hipStream_t stream)
{
    const float* X  = (const float*)d_in[0];
    const float* W  = (const float*)d_in[1];
    const float* Bv = (const float*)d_in[2];
    float* out = (float*)d_out;

    // ws: sum 37.7 MB + gsum 4.7 MB + ginfl 1.05 MB + infl 8.4 MB = 51.9 MB
    float* sum   = (float*)d_ws;
    float* gsum  = sum   + (size_t)BB * C  * NSUM * DD;
    float* ginfl = gsum  + (size_t)BB * NG * NSUM * DD;
    float* infl  = ginfl + (size_t)BB * NG * KK   * DD;

    pass1_summaries<<<BB * C, 256, 0, stream>>>(X, W, Bv, sum);

    void* args[] = {(void*)&sum, (void*)&gsum, (void*)&ginfl, (void*)&infl};
    hipLaunchCooperativeKernel((const void*)pass2_fused, dim3(BB * NG), dim3(256),
                               args, 0, stream);

    pass3_scan<<<BB * C, 256, 0, stream>>>(X, W, Bv, infl, out);
}

// Round 8
// 167.601 us; speedup vs baseline: 1.2734x; 1.2734x over previous
//
#include <hip/hip_runtime.h>
#include <math.h>

// LayerSumSimple: K-level chained cummax-of-sums == max-plus affine scan with
// 8-element state s:  s[k] <- max(s[k], s[k-1] + g_k(t)),  g_k = x*w[k]+b[k].
// Round-14: round-3 5-pass skeleton (best-measured family, ~167-169us), with
// ONE retained change for clean attribution: pass1 uses BAND-2 pair-steps
// (two elementary steps fused; every update a 3-input max -> v_max3_f32;
// 58 ops/step vs 72). pair_sum is HW-verified correct (round-7 absmax=0).
// Fusion lines measured and rejected: spin-flag lookback (+30us latency tail,
// r4/r5), cooperative grid.sync (+30us, r7: 50.5us pass2_fused vs ~12us for
// three kernels). Launch gaps (~2-3us) are cheaper than any cross-block sync.
// All workspace arrays use PLANE layout: plane i of region r at
// base[r*NPLANES*DD + i*DD + d] -> lane d accesses are fully coalesced.
namespace {
constexpr int BB   = 8;
constexpr int TT   = 8192;
constexpr int DD   = 256;
constexpr int KK   = 8;
constexpr int TOUT = TT - KK + 1;       // 8185
constexpr int NSUM = 36;                // 8 c-vec + 28 strict-lower A
constexpr int C    = 128;               // chunks per sequence
constexpr int L    = TT / C;            // 64
constexpr int G    = 8;                 // chunks per group
constexpr int NG   = C / G;             // 16
constexpr int MSTR = NSUM * DD;         // float stride between map regions

// strict-lower-triangle linear index: k in [1,8), j < k  ->  [0,28)
__host__ __device__ __forceinline__ constexpr int alin(int k, int j) {
    return k * (k - 1) / 2 + j;
}
// plane index of A[k][j] in the 36-plane map layout (planes 0..7 = c-vec)
__host__ __device__ __forceinline__ constexpr int tri(int k, int j) {
    return 8 + alin(k, j);
}

__device__ __forceinline__ float max3(float a, float b, float c) {
    return fmaxf(fmaxf(a, b), c);       // clang fuses to v_max3_f32
}

// TWO fused time-steps of the summary recurrence (band-2 pair map applied to
// the accumulated triangular map). Descending k: rows k-1,k-2 read OLD values.
__device__ __forceinline__ void pair_sum(float xa, float xb,
                                         const float (&wk)[KK],
                                         const float (&bk)[KK],
                                         float (&a)[28], float (&cv)[KK])
{
    float gA[KK], gB[KK], d1[KK], d2[KK];   // d2 valid for k>=1
    #pragma unroll
    for (int k = 0; k < KK; ++k) gA[k] = fmaf(xa, wk[k], bk[k]);
    #pragma unroll
    for (int k = 0; k < KK; ++k) gB[k] = fmaf(xb, wk[k], bk[k]);
    #pragma unroll
    for (int k = 0; k < KK; ++k) d1[k] = fmaxf(gA[k], gB[k]);
    #pragma unroll
    for (int k = 1; k < KK; ++k) d2[k] = gA[k - 1] + gB[k];

    #pragma unroll
    for (int k = KK - 1; k >= 2; --k) {
        #pragma unroll
        for (int j = 0; j <= k - 3; ++j)
            a[alin(k, j)] = max3(a[alin(k, j)], d1[k] + a[alin(k - 1, j)],
                                 d2[k] + a[alin(k - 2, j)]);
        // j = k-2: diag a[k-2][k-2] == 0
        a[alin(k, k - 2)] = max3(a[alin(k, k - 2)],
                                 d1[k] + a[alin(k - 1, k - 2)], d2[k]);
        // j = k-1: diag a[k-1][k-1] == 0; a[k-2][k-1] = -inf
        a[alin(k, k - 1)] = fmaxf(a[alin(k, k - 1)], d1[k]);
        cv[k] = max3(cv[k], d1[k] + cv[k - 1], d2[k] + cv[k - 2]);
    }
    a[alin(1, 0)] = fmaxf(a[alin(1, 0)], d1[1]);
    cv[1] = max3(cv[1], d1[1] + cv[0], d2[1]);
    cv[0] = fmaxf(cv[0], d1[0]);
}

// ---- pass 1: one block per (b, chunk); thread d = channel ----
__global__ __launch_bounds__(256) void pass1_summaries(
    const float* __restrict__ X, const float* __restrict__ W,
    const float* __restrict__ Bv, float* __restrict__ sum)
{
    constexpr int U  = 8;
    constexpr int NB = L / U;           // 8
    const int b = blockIdx.x / C;
    const int c = blockIdx.x % C;
    const int d = threadIdx.x;

    float wk[KK], bk[KK];
    #pragma unroll
    for (int k = 0; k < KK; ++k) { wk[k] = W[k * DD + d]; bk[k] = Bv[k * DD + d]; }

    float cv[KK];
    float a[28];
    #pragma unroll
    for (int k = 0; k < KK; ++k) cv[k] = -INFINITY;
    #pragma unroll
    for (int i = 0; i < 28; ++i) a[i] = -INFINITY;

    const float* xp = X + ((size_t)(b * TT + c * L)) * DD + d;
    float x0[U], x1[U];
    #pragma unroll
    for (int u = 0; u < U; ++u) x0[u] = xp[u * DD];

    // dynamic loop: 16-step body; prefetch distance = 8 steps
    #pragma unroll 1
    for (int ib = 0; ib + 2 < NB; ib += 2) {
        #pragma unroll
        for (int u = 0; u < U; ++u) x1[u] = xp[(U + u) * DD];
        #pragma unroll
        for (int u = 0; u < U / 2; ++u) pair_sum(x0[2 * u], x0[2 * u + 1], wk, bk, a, cv);
        #pragma unroll
        for (int u = 0; u < U; ++u) x0[u] = xp[(2 * U + u) * DD];
        #pragma unroll
        for (int u = 0; u < U / 2; ++u) pair_sum(x1[2 * u], x1[2 * u + 1], wk, bk, a, cv);
        xp += 2 * U * DD;
    }
    // tail: batches NB-2 (in x0) and NB-1
    #pragma unroll
    for (int u = 0; u < U; ++u) x1[u] = xp[(U + u) * DD];
    #pragma unroll
    for (int u = 0; u < U / 2; ++u) pair_sum(x0[2 * u], x0[2 * u + 1], wk, bk, a, cv);
    #pragma unroll
    for (int u = 0; u < U / 2; ++u) pair_sum(x1[2 * u], x1[2 * u + 1], wk, bk, a, cv);

    // plane-layout store: 36 coalesced 1KB stores
    float* sp = sum + (size_t)blockIdx.x * MSTR + d;   // region = b*C + c
    #pragma unroll
    for (int k = 0; k < KK; ++k) sp[k * DD] = cv[k];
    #pragma unroll
    for (int i = 0; i < 28; ++i) sp[(8 + i) * DD] = a[i];
}

// plane-layout map load: 36 coalesced scalar loads into registers
__device__ __forceinline__ void ld_map(const float* __restrict__ p,
                                       float (&m)[NSUM])
{
    #pragma unroll
    for (int i = 0; i < NSUM; ++i) m[i] = p[i * DD];
}

// s <- apply(map m, s)
__device__ __forceinline__ void apply_map(const float (&m)[NSUM], float (&s)[KK])
{
    float ns[KK];
    #pragma unroll
    for (int k = 0; k < KK; ++k) ns[k] = fmaxf(m[k], s[k]);   // c[k], diag
    #pragma unroll
    for (int k = 1; k < KK; ++k) {
        #pragma unroll
        for (int j = 0; j < k; ++j) ns[k] = fmaxf(ns[k], m[tri(k, j)] + s[j]);
    }
    #pragma unroll
    for (int k = 0; k < KK; ++k) s[k] = ns[k];
}

// (R,cv) <- compose(map m, (R,cv))   [m applied AFTER accumulated (R,cv)]
__device__ __forceinline__ void compose_map(const float (&m)[NSUM],
                                            float (&R)[KK][KK], float (&cv)[KK])
{
    float nc[KK];
    #pragma unroll
    for (int i = 0; i < KK; ++i) {
        float v = fmaxf(m[i], cv[i]);
        #pragma unroll
        for (int j = 0; j < i; ++j) v = fmaxf(v, m[tri(i, j)] + cv[j]);
        nc[i] = v;
    }
    float nR[KK][KK];
    #pragma unroll
    for (int i = 1; i < KK; ++i) {
        #pragma unroll
        for (int j = 0; j < i; ++j) {
            float v = fmaxf(R[i][j], m[tri(i, j)]);
            #pragma unroll
            for (int mm = j + 1; mm < i; ++mm)
                v = fmaxf(v, m[tri(i, mm)] + R[mm][j]);
            nR[i][j] = v;
        }
    }
    #pragma unroll
    for (int i = 0; i < KK; ++i) {
        cv[i] = nc[i];
        #pragma unroll
        for (int j = 0; j < i; ++j) R[i][j] = nR[i][j];
    }
}

// ---- pass 2a: one block per (b, group); compose G chunk maps ----
__global__ __launch_bounds__(256) void pass2a_groups(
    const float* __restrict__ sum, float* __restrict__ gsum)
{
    const int b = blockIdx.x / NG;
    const int g = blockIdx.x % NG;
    const int d = threadIdx.x;

    float R[KK][KK], cv[KK];
    #pragma unroll
    for (int i = 0; i < KK; ++i) {
        cv[i] = -INFINITY;
        #pragma unroll
        for (int j = 0; j < KK; ++j) R[i][j] = -INFINITY;
    }

    const float* mp = sum + ((size_t)(b * C + g * G)) * MSTR + d;
    float m0[NSUM], m1[NSUM];
    ld_map(mp, m0);
    #pragma unroll 1
    for (int ci = 0; ci + 2 < G; ci += 2) {
        ld_map(mp + MSTR, m1);
        compose_map(m0, R, cv);
        ld_map(mp + 2 * MSTR, m0);
        compose_map(m1, R, cv);
        mp += 2 * MSTR;
    }
    ld_map(mp + MSTR, m1);
    compose_map(m0, R, cv);
    compose_map(m1, R, cv);

    float* gp = gsum + (size_t)blockIdx.x * MSTR + d;  // region = b*NG + g
    #pragma unroll
    for (int i = 0; i < KK; ++i) gp[i * DD] = cv[i];
    #pragma unroll
    for (int i = 1; i < KK; ++i) {
        #pragma unroll
        for (int j = 0; j < i; ++j) gp[tri(i, j) * DD] = R[i][j];
    }
}

// ---- pass 2b: one block per b; serial apply over NG group maps ----
__global__ __launch_bounds__(256) void pass2b_scan_groups(
    const float* __restrict__ gsum, float* __restrict__ ginfl)
{
    const int b = blockIdx.x;
    const int d = threadIdx.x;

    float s[KK];
    #pragma unroll
    for (int k = 0; k < KK; ++k) s[k] = -INFINITY;

    const float* mp = gsum + (size_t)b * NG * MSTR + d;
    float* ip = ginfl + (size_t)b * NG * KK * DD + d;
    float m0[NSUM], m1[NSUM];
    ld_map(mp, m0);
    #pragma unroll 1
    for (int g = 0; g + 2 < NG; g += 2) {
        ld_map(mp + MSTR, m1);
        #pragma unroll
        for (int k = 0; k < KK; ++k) ip[k * DD] = s[k];      // inflow BEFORE g
        apply_map(m0, s);
        ld_map(mp + 2 * MSTR, m0);
        #pragma unroll
        for (int k = 0; k < KK; ++k) ip[KK * DD + k * DD] = s[k];
        apply_map(m1, s);
        mp += 2 * MSTR;
        ip += 2 * KK * DD;
    }
    ld_map(mp + MSTR, m1);
    #pragma unroll
    for (int k = 0; k < KK; ++k) ip[k * DD] = s[k];
    apply_map(m0, s);
    #pragma unroll
    for (int k = 0; k < KK; ++k) ip[KK * DD + k * DD] = s[k];
    apply_map(m1, s);
}

// ---- pass 2c: one block per (b, group); replay chunk maps -> chunk inflows ----
__global__ __launch_bounds__(256) void pass2c_chunk_inflows(
    const float* __restrict__ sum, const float* __restrict__ ginfl,
    float* __restrict__ infl)
{
    const int b = blockIdx.x / NG;
    const int g = blockIdx.x % NG;
    const int d = threadIdx.x;

    float s[KK];
    {
        const float* gp = ginfl + (size_t)blockIdx.x * KK * DD + d;  // region = b*NG+g
        #pragma unroll
        for (int k = 0; k < KK; ++k) s[k] = gp[k * DD];
    }

    const float* mp = sum + ((size_t)(b * C + g * G)) * MSTR + d;
    float* ip = infl + ((size_t)(b * C + g * G)) * KK * DD + d;
    float m0[NSUM], m1[NSUM];
    ld_map(mp, m0);
    #pragma unroll 1
    for (int ci = 0; ci + 2 < G; ci += 2) {
        ld_map(mp + MSTR, m1);
        #pragma unroll
        for (int k = 0; k < KK; ++k) ip[k * DD] = s[k];      // inflow BEFORE c
        apply_map(m0, s);
        ld_map(mp + 2 * MSTR, m0);
        #pragma unroll
        for (int k = 0; k < KK; ++k) ip[KK * DD + k * DD] = s[k];
        apply_map(m1, s);
        mp += 2 * MSTR;
        ip += 2 * KK * DD;
    }
    ld_map(mp + MSTR, m1);
    #pragma unroll
    for (int k = 0; k < KK; ++k) ip[k * DD] = s[k];
    apply_map(m0, s);
    #pragma unroll
    for (int k = 0; k < KK; ++k) ip[KK * DD + k * DD] = s[k];
    apply_map(m1, s);
}

// ---- pass 3: one block per (b, chunk); scan from inflow, emit outputs ----
__device__ __forceinline__ void step_scan(float x, const float (&wk)[KK],
                                          const float (&bk)[KK], float (&s)[KK])
{
    float g[KK];
    #pragma unroll
    for (int k = 0; k < KK; ++k) g[k] = fmaf(x, wk[k], bk[k]);
    #pragma unroll
    for (int k = KK - 1; k >= 1; --k) s[k] = fmaxf(s[k], s[k - 1] + g[k]);
    s[0] = fmaxf(s[0], g[0]);
}

__global__ __launch_bounds__(256) void pass3_scan(
    const float* __restrict__ X, const float* __restrict__ W,
    const float* __restrict__ Bv, const float* __restrict__ infl,
    float* __restrict__ out)
{
    constexpr int U  = 16;              // deep prefetch: 16 rows in flight
    constexpr int NB = L / U;           // 4
    const int b = blockIdx.x / C;
    const int c = blockIdx.x % C;
    const int d = threadIdx.x;

    float wk[KK], bk[KK];
    #pragma unroll
    for (int k = 0; k < KK; ++k) { wk[k] = W[k * DD + d]; bk[k] = Bv[k * DD + d]; }

    float s[KK];
    {
        const float* ip = infl + (size_t)blockIdx.x * KK * DD + d;   // region = b*C+c
        #pragma unroll
        for (int k = 0; k < KK; ++k) s[k] = ip[k * DD];
    }

    const int t0 = c * L;
    const float* xp = X + ((size_t)(b * TT + t0)) * DD + d;
    // base indexed by cumulative in-chunk step t only (op never advances)
    float* op = out + (size_t)b * TOUT * DD + (ptrdiff_t)(t0 - (KK - 1)) * DD + d;

    float x0[U], x1[U];
    #pragma unroll
    for (int u = 0; u < U; ++u) x0[u] = xp[u * DD];

    int t = 0;                                   // step within chunk
    #pragma unroll 1
    for (int ib = 0; ib + 2 < NB; ib += 2) {
        #pragma unroll
        for (int u = 0; u < U; ++u) x1[u] = xp[(U + u) * DD];
        #pragma unroll
        for (int u = 0; u < U; ++u) {
            step_scan(x0[u], wk, bk, s);
            if (t0 + t >= KK - 1) __builtin_nontemporal_store(s[KK - 1], &op[t * DD]);
            ++t;
        }
        #pragma unroll
        for (int u = 0; u < U; ++u) x0[u] = xp[(2 * U + u) * DD];
        #pragma unroll
        for (int u = 0; u < U; ++u) {
            step_scan(x1[u], wk, bk, s);
            if (t0 + t >= KK - 1) __builtin_nontemporal_store(s[KK - 1], &op[t * DD]);
            ++t;
        }
        xp += 2 * U * DD;
    }
    #pragma unroll
    for (int u = 0; u < U; ++u) x1[u] = xp[(U + u) * DD];
    #pragma unroll
    for (int u = 0; u < U; ++u) {
        step_scan(x0[u], wk, bk, s);
        if (t0 + t >= KK - 1) __builtin_nontemporal_store(s[KK - 1], &op[t * DD]);
        ++t;
    }
    #pragma unroll
    for (int u = 0; u < U; ++u) {
        step_scan(x1[u], wk, bk, s);
        if (t0 + t >= KK - 1) __builtin_nontemporal_store(s[KK - 1], &op[t * DD]);
        ++t;
    }
}
} // namespace

extern "C" void kernel_launch(void* const* d_in, const int* in_sizes, int n_in,
                              void* d_out, int out_size, void* d_ws, size_t ws_size,
                              hipStream_t stream)
{
    const float* X  = (const float*)d_in[0];
    const float* W  = (const float*)d_in[1];
    const float* Bv = (const float*)d_in[2];
    float* out = (float*)d_out;

    // ws: sum 37.7 MB + gsum 4.7 MB + ginfl 1.05 MB + infl 8.4 MB = 51.9 MB
    float* sum   = (float*)d_ws;
    float* gsum  = sum   + (size_t)BB * C  * NSUM * DD;
    float* ginfl = gsum  + (size_t)BB * NG * NSUM * DD;
    float* infl  = ginfl + (size_t)BB * NG * KK   * DD;

    pass1_summaries<<<BB * C, 256, 0, stream>>>(X, W, Bv, sum);
    pass2a_groups<<<BB * NG, 256, 0, stream>>>(sum, gsum);
    pass2b_scan_groups<<<BB, 256, 0, stream>>>(gsum, ginfl);
    pass2c_chunk_inflows<<<BB * NG, 256, 0, stream>>>(sum, ginfl, infl);
    pass3_scan<<<BB * C, 256, 0, stream>>>(X, W, Bv, infl, out);
}